// Round 8
// baseline (498.234 us; speedup 1.0000x reference)
//
#include <hip/hip_runtime.h>

#define LL 128
#define NT 256
#define NW 8256            // 128*129/2 packed diagonal-major triangular size

__device__ __forceinline__ float softplus_f(float x) { return log1pf(__expf(x)); }

// LDS-visibility-only barrier: waits LDS ops, leaves global prefetches in flight.
__device__ __forceinline__ void lds_barrier() {
    asm volatile("s_waitcnt lgkmcnt(0)" ::: "memory");
    __builtin_amdgcn_s_barrier();
    asm volatile("" ::: "memory");
}

// Diagonal-major packed offset: cell (i, i+w) lives at T(w)+i.
__device__ __forceinline__ int Toff(int w) { return LL * w - ((w * (w - 1)) >> 1); }

// LDS slabs (all NW floats, packed diagonal-major):
//   Ad  : inside values A
//   SPd : softplus(s) per cell (written at finalize; powers outside + epilogue)
//   GLd : left-child gradient accumulators
//   GRd : right-child gradient accumulators
// Outside scatter addresses == inside gather addresses (a1 = left child slot,
// a2 = right child slot) — unique writer per slot per phase, no atomics.
extern "C" __global__ __launch_bounds__(NT, 1) void cky_kernel(
    const float* __restrict__ scores,
    const int* __restrict__ seq_lens,
    float* __restrict__ Z_out,
    float* __restrict__ marg_out)
{
    extern __shared__ float smem[];
    float* Ad  = smem;
    float* SPd = smem + NW;
    float* GLd = smem + 2 * NW;
    float* GRd = smem + 3 * NW;

    const int b   = blockIdx.x;
    const int tid = threadIdx.x;
    const float* s = scores + (size_t)b * LL * LL;
    float* marg = marg_out + (size_t)b * LL * LL;
    const int len = seq_lens[b];

    // ---- init: zero gradient accumulators, width-0 diagonal, s-prefetch ----
    for (int idx = tid; idx < 2 * NW; idx += NT) GLd[idx] = 0.f;
    float Aprev = 0.f, sv0 = 0.f, sv1 = 0.f;
    if (tid < LL) {
        const float sp = softplus_f(s[tid * LL + tid]);
        Ad[tid]  = sp;
        SPd[tid] = sp;
        Aprev = sp;                                   // M for phase w=1
        if (tid + 1 < LL) sv0 = s[tid * LL + tid + 1];   // s for w=1
        if (tid + 2 < LL) sv1 = s[tid * LL + tid + 2];   // s for w=2
    }
    lds_barrier();

    const int wswitch = (len < 64) ? len : 64;   // per-lane-cell for w < wswitch

    // ================= INSIDE =================
    // per-lane-cell phases: lane l owns cell (l, l+w); uniform w-trip loop,
    // no shuffles; M = own previous-width value (register).
    for (int w = 1; w < wswitch; ++w) {
        const int cells = len - w;
        if (tid < cells) {
            const int l = tid;
            float svn = 0.f;
            if (w + 2 < wswitch) svn = s[l * LL + l + w + 2];   // prefetch 2 ahead
            int a1 = l;                                  // T(0)+l  : A[l,l+e]
            const int Tw1 = Toff(w - 1);
            int a2 = Tw1 + l + 1;                        // T(w-1)+l+1 : A[l+e+1,l+w]
            int d1 = LL, d2 = w - LL - 1;
            const float M = Aprev;
            float acc = 0.f;
            #pragma unroll 4
            for (int e = 0; e < w; ++e) {
                acc += __expf(Ad[a1] + Ad[a2] - M);
                a1 += d1; a2 += d2; --d1; --d2;
            }
            const float Sij = M + __logf(acc);           // acc >= exp(A[j,j]-M+A..)>0
            const float sp = softplus_f(sv0);
            Aprev = Sij + sp;
            const int p = Tw1 + (LL - (w - 1)) + l;      // Toff(w)+l
            Ad[p]  = Aprev;
            SPd[p] = sp;
            sv0 = sv1; sv1 = svn;                        // rotate prefetch ring
        }
        lds_barrier();
    }

    // g-split phases: w >= 64, cells = len-w <= 64; g lanes per cell.
    for (int w = 64; w < len; ++w) {
        const int cells = len - w;
        const int clc = (cells > 1) ? (32 - __clz(cells - 1)) : 0;
        int gsh = 8 - clc; if (gsh > 6) gsh = 6;
        const int g = 1 << gsh, gg = g * g;
        const int gid = tid >> gsh, v = tid & (g - 1);
        if (gid < cells) {
            const int i = gid;
            const float sv = s[i * LL + i + w];          // broadcast load, hidden by loop
            const int Tw1 = Toff(w - 1);
            const float M = Ad[Tw1 + i];                 // broadcast
            const int m0 = w - 1 - v;
            int a1 = Toff(v) + i;
            int a2 = Toff(m0) + i + v + 1;
            int d1 = LL * g - g * v - ((g * (g - 1)) >> 1);
            int d2 = g * m0 - LL * g - ((g * (g + 1)) >> 1) + g;
            float acc = 0.f;
            #pragma unroll 4
            for (int e = v; e < w; e += g) {
                acc += __expf(Ad[a1] + Ad[a2] - M);
                a1 += d1; a2 += d2; d1 -= gg; d2 -= gg;
            }
            for (int off = g >> 1; off; off >>= 1) acc += __shfl_xor(acc, off);
            if (v == 0) {
                const float Sij = M + __logf(acc);
                const float sp = softplus_f(sv);
                const int p = Tw1 + (LL - (w - 1)) + i;  // Toff(w)+i
                Ad[p]  = Sij + sp;
                SPd[p] = sp;
            }
        }
        lds_barrier();
    }

    if (tid == 0) Z_out[b] = Ad[Toff(len - 1)];

    // ================= OUTSIDE (race-free paired scatter) =================
    // Parent (i,i+w): t_e = exp(A[i,i+e] + A[i+e+1,i+w] - (S - log Gp)) <= 1.
    //   left child slot  = a1 = Toff(e)+i        -> GLd
    //   right child slot = a2 = Toff(w-1-e)+i+e+1 -> GRd
    for (int w = len - 1; w >= 64; --w) {                // g-split phases
        const int cells = len - w;
        const int clc = (cells > 1) ? (32 - __clz(cells - 1)) : 0;
        int gsh = 8 - clc; if (gsh > 6) gsh = 6;
        const int g = 1 << gsh, gg = g * g;
        const int gid = tid >> gsh, v = tid & (g - 1);
        if (gid < cells) {
            const int i = gid;
            const int Tw1 = Toff(w - 1);
            const int p = Tw1 + (LL - (w - 1)) + i;      // Toff(w)+i
            float Gp = GLd[p] + GRd[p];
            if (i == 0 && w == len - 1) Gp += 1.f;       // root seed
            if (Gp > 0.f) {
                const float SL = Ad[p] - SPd[p] - __logf(Gp);
                const int m0 = w - 1 - v;
                int a1 = Toff(v) + i;
                int a2 = Toff(m0) + i + v + 1;
                int d1 = LL * g - g * v - ((g * (g - 1)) >> 1);
                int d2 = g * m0 - LL * g - ((g * (g + 1)) >> 1) + g;
                #pragma unroll 4
                for (int e = v; e < w; e += g) {
                    const float tv = __expf(Ad[a1] + Ad[a2] - SL);
                    GLd[a1] += tv;
                    GRd[a2] += tv;
                    a1 += d1; a2 += d2; d1 -= gg; d2 -= gg;
                }
            }
        }
        lds_barrier();
    }

    const int wtop = (len - 1 < 63) ? (len - 1) : 63;
    for (int w = wtop; w >= 1; --w) {                    // per-lane-cell phases
        const int cells = len - w;
        if (tid < cells) {
            const int l = tid;
            const int Tw1 = Toff(w - 1);
            const int p = Tw1 + (LL - (w - 1)) + l;      // Toff(w)+l
            float Gp = GLd[p] + GRd[p];
            if (l == 0 && w == len - 1) Gp += 1.f;       // root seed (len<=64 case)
            if (Gp > 0.f) {
                const float SL = Ad[p] - SPd[p] - __logf(Gp);
                int a1 = l;
                int a2 = Tw1 + l + 1;
                int d1 = LL, d2 = w - LL - 1;
                #pragma unroll 4
                for (int e = 0; e < w; ++e) {
                    const float tv = __expf(Ad[a1] + Ad[a2] - SL);
                    GLd[a1] += tv;
                    GRd[a2] += tv;
                    a1 += d1; a2 += d2; --d1; --d2;
                }
            }
        }
        lds_barrier();
    }

    // ================= epilogue: marg (coalesced), zero outside triangle ====
    for (int idx = tid; idx < LL * LL; idx += NT) {
        const int r = idx >> 7, c = idx & (LL - 1);
        float m = 0.f;
        if (c >= r && c < len) {
            const int w = c - r;
            const int p = Toff(w) + r;
            float G = GLd[p] + GRd[p];
            if (r == 0 && c == len - 1) G += 1.f;        // root
            m = G * (1.f - __expf(-SPd[p]));             // G * sigmoid(s)
        }
        marg[idx] = m;
    }
}

extern "C" void kernel_launch(void* const* d_in, const int* in_sizes, int n_in,
                              void* d_out, int out_size, void* d_ws, size_t ws_size,
                              hipStream_t stream) {
    const float* scores  = (const float*)d_in[0];
    const int* seq_lens  = (const int*)d_in[1];
    const int B = in_sizes[1];              // 32
    float* out = (float*)d_out;
    float* Z_out = out;                     // B floats
    float* marg  = out + B;                 // B*L*L floats

    const size_t lds_bytes = (size_t)4 * NW * sizeof(float);  // 132096 B
    hipFuncSetAttribute((const void*)cky_kernel,
                        hipFuncAttributeMaxDynamicSharedMemorySize,
                        (int)lds_bytes);
    cky_kernel<<<B, NT, lds_bytes, stream>>>(scores, seq_lens, Z_out, marg);
}

// Round 9
// 317.880 us; speedup vs baseline: 1.5674x; 1.5674x over previous
//
#include <hip/hip_runtime.h>

#define LL 128
#define NT 1024
#define NW 8256            // 128*129/2 packed triangular size
#define WSW 16             // per-lane-cell mode for w < WSW, g-split above

__device__ __forceinline__ float softplus_f(float x) { return log1pf(__expf(x)); }

// LDS-visibility-only barrier: waits LDS ops, leaves global ops un-drained.
__device__ __forceinline__ void lds_barrier() {
    asm volatile("s_waitcnt lgkmcnt(0)" ::: "memory");
    __builtin_amdgcn_s_barrier();
    asm volatile("" ::: "memory");
}

// Diagonal-major packed offset: cell (i, i+w) lives at Toff(w)+i.
__device__ __forceinline__ int Toff(int w) { return LL * w - ((w * (w - 1)) >> 1); }

// LDS slabs (each NW floats, packed diagonal-major):
//   Ad  : inside values A
//   SPd : softplus(s) per cell (preloaded once; no global reads in phase loops)
//   GLd : left-child gradient accumulators
//   GRd : right-child gradient accumulators
extern "C" __global__ __launch_bounds__(NT, 1) void cky_kernel(
    const float* __restrict__ scores,
    const int* __restrict__ seq_lens,
    float* __restrict__ Z_out,
    float* __restrict__ marg_out)
{
    extern __shared__ float smem[];
    float* Ad  = smem;
    float* SPd = smem + NW;
    float* GLd = smem + 2 * NW;
    float* GRd = smem + 3 * NW;

    const int b   = blockIdx.x;
    const int tid = threadIdx.x;
    const float* s = scores + (size_t)b * LL * LL;
    float* marg = marg_out + (size_t)b * LL * LL;
    const int len = seq_lens[b];

    // ---- init: preload softplus(s) (coalesced global reads), zero grads ----
    for (int idx = tid; idx < LL * LL; idx += NT) {
        const int r = idx >> 7, c = idx & (LL - 1);
        if (c >= r) SPd[Toff(c - r) + r] = softplus_f(s[idx]);
    }
    for (int idx = tid; idx < 2 * NW; idx += NT) GLd[idx] = 0.f;
    lds_barrier();

    float Aprev = 0.f;
    if (tid < LL) {
        Aprev = SPd[tid];          // width-0: A[i][i] = softplus(s_ii)
        Ad[tid] = Aprev;
    }
    lds_barrier();

    const int wsw = (len < WSW) ? len : WSW;

    // ================= INSIDE =================
    // Per-lane-cell phases (w < WSW): lane l owns cell (l, l+w); serial loop
    // of <=15 iters, no shuffles; LSE shift M = own previous-width A (register).
    for (int w = 1; w < wsw; ++w) {
        const int cells = len - w;
        if (tid < cells) {
            const int l = tid;
            const int Tw1 = Toff(w - 1);
            int a1 = l;                                  // A[l, l+e]     @ Toff(e)+l
            int a2 = Tw1 + l + 1;                        // A[l+e+1, l+w] @ Toff(w-1-e)+l+e+1
            int d1 = LL, d2 = w - LL - 1;
            const float M = Aprev;
            float acc = 0.f;
            #pragma unroll 4
            for (int e = 0; e < w; ++e) {
                acc += __expf(Ad[a1] + Ad[a2] - M);
                a1 += d1; a2 += d2; --d1; --d2;
            }
            const int p = Tw1 + (LL - (w - 1)) + l;      // Toff(w)+l
            const float Sij = M + __logf(acc);           // acc >= exp(A[j,j]) >= 1
            Aprev = Sij + SPd[p];
            Ad[p] = Aprev;
        }
        lds_barrier();
    }

    // g-split phases (w >= WSW): g lanes per cell, <=~4 trips, log2(g) shuffles.
    for (int w = WSW; w < len; ++w) {
        const int cells = len - w;
        const int clw = 32 - __clz(w - 1);               // ceil(log2 w), w>=16
        const int clc = (cells > 1) ? (32 - __clz(cells - 1)) : 0;
        int gsh = clw - 2;
        const int cap = 10 - clc; if (gsh > cap) gsh = cap;
        if (gsh > 6) gsh = 6;
        if (gsh < 0) gsh = 0;
        const int g = 1 << gsh, gg = g * g;
        const int gid = tid >> gsh, v = tid & (g - 1);
        if (gid < cells) {
            const int i = gid;
            const int Tw1 = Toff(w - 1);
            const float M = Ad[Tw1 + i];                 // broadcast; overlaps loads
            const int m0 = w - 1 - v;
            int a1 = Toff(v) + i;
            int a2 = Toff(m0) + i + v + 1;
            int d1 = LL * g - g * v - ((g * (g - 1)) >> 1);
            int d2 = g * m0 - LL * g - ((g * (g + 1)) >> 1) + g;
            float acc = 0.f;
            #pragma unroll 4
            for (int e = v; e < w; e += g) {
                acc += __expf(Ad[a1] + Ad[a2] - M);
                a1 += d1; a2 += d2; d1 -= gg; d2 -= gg;
            }
            for (int off = g >> 1; off; off >>= 1) acc += __shfl_xor(acc, off);
            if (v == 0) {
                const int p = Tw1 + (LL - (w - 1)) + i;  // Toff(w)+i
                Ad[p] = M + __logf(acc) + SPd[p];
            }
        }
        lds_barrier();
    }

    if (tid == 0) Z_out[b] = Ad[Toff(len - 1)];

    // ================= OUTSIDE (race-free paired scatter) =================
    // Parent (i,i+w): t_e = exp(A[i,i+e] + A[i+e+1,i+w] - (S - log Gp)) <= 1.
    // Scatter slots == gather addresses (a1 -> GLd, a2 -> GRd); each slot has
    // a unique writer per phase (injective (i,e) -> slot maps), no atomics.
    for (int w = len - 1; w >= WSW; --w) {               // g-split phases
        const int cells = len - w;
        const int clw = 32 - __clz(w - 1);
        const int clc = (cells > 1) ? (32 - __clz(cells - 1)) : 0;
        int gsh = clw - 2;
        const int cap = 10 - clc; if (gsh > cap) gsh = cap;
        if (gsh > 6) gsh = 6;
        if (gsh < 0) gsh = 0;
        const int g = 1 << gsh, gg = g * g;
        const int gid = tid >> gsh, v = tid & (g - 1);
        if (gid < cells) {
            const int i = gid;
            const int Tw1 = Toff(w - 1);
            const int p = Tw1 + (LL - (w - 1)) + i;      // Toff(w)+i
            float Gp = GLd[p] + GRd[p];
            if (i == 0 && w == len - 1) Gp += 1.f;       // root seed
            if (Gp > 0.f) {
                const float SL = Ad[p] - SPd[p] - __logf(Gp);
                const int m0 = w - 1 - v;
                int a1 = Toff(v) + i;
                int a2 = Toff(m0) + i + v + 1;
                int d1 = LL * g - g * v - ((g * (g - 1)) >> 1);
                int d2 = g * m0 - LL * g - ((g * (g + 1)) >> 1) + g;
                #pragma unroll 4
                for (int e = v; e < w; e += g) {
                    const float tv = __expf(Ad[a1] + Ad[a2] - SL);
                    GLd[a1] += tv;
                    GRd[a2] += tv;
                    a1 += d1; a2 += d2; d1 -= gg; d2 -= gg;
                }
            }
        }
        lds_barrier();
    }

    const int wtop = (len - 1 < WSW - 1) ? (len - 1) : (WSW - 1);
    for (int w = wtop; w >= 1; --w) {                    // per-lane-cell phases
        const int cells = len - w;
        if (tid < cells) {
            const int l = tid;
            const int Tw1 = Toff(w - 1);
            const int p = Tw1 + (LL - (w - 1)) + l;      // Toff(w)+l
            float Gp = GLd[p] + GRd[p];
            if (l == 0 && w == len - 1) Gp += 1.f;       // root seed (small-len case)
            if (Gp > 0.f) {
                const float SL = Ad[p] - SPd[p] - __logf(Gp);
                int a1 = l;
                int a2 = Tw1 + l + 1;
                int d1 = LL, d2 = w - LL - 1;
                #pragma unroll 4
                for (int e = 0; e < w; ++e) {
                    const float tv = __expf(Ad[a1] + Ad[a2] - SL);
                    GLd[a1] += tv;
                    GRd[a2] += tv;
                    a1 += d1; a2 += d2; --d1; --d2;
                }
            }
        }
        lds_barrier();
    }

    // ================= epilogue: marg (coalesced) =================
    for (int idx = tid; idx < LL * LL; idx += NT) {
        const int r = idx >> 7, c = idx & (LL - 1);
        float m = 0.f;
        if (c >= r && c < len) {
            const int p = Toff(c - r) + r;
            float G = GLd[p] + GRd[p];
            if (r == 0 && c == len - 1) G += 1.f;        // root
            m = G * (1.f - __expf(-SPd[p]));             // G * sigmoid(s)
        }
        marg[idx] = m;
    }
}

extern "C" void kernel_launch(void* const* d_in, const int* in_sizes, int n_in,
                              void* d_out, int out_size, void* d_ws, size_t ws_size,
                              hipStream_t stream) {
    const float* scores  = (const float*)d_in[0];
    const int* seq_lens  = (const int*)d_in[1];
    const int B = in_sizes[1];              // 32
    float* out = (float*)d_out;
    float* Z_out = out;                     // B floats
    float* marg  = out + B;                 // B*L*L floats

    const size_t lds_bytes = (size_t)4 * NW * sizeof(float);  // 132096 B
    hipFuncSetAttribute((const void*)cky_kernel,
                        hipFuncAttributeMaxDynamicSharedMemorySize,
                        (int)lds_bytes);
    cky_kernel<<<B, NT, lds_bytes, stream>>>(scores, seq_lens, Z_out, marg);
}